// Round 5
// baseline (100.547 us; speedup 1.0000x reference)
//
#include <hip/hip_runtime.h>

#define B 4
#define L 200
#define N 160
#define HS 768
#define HD 256
#define C 16

#define KP 784             // padded K: 768 data + 1 gate(bias) + 15 zero
#define WJ 48              // fused cols: A(16) | B(16) | T(16)
#define KS 4               // split-k slices
#define KSL (KP / KS)      // 196
#define NROW (B * N)       // 640
#define NBLK 256
#define NTHR 256

// Device-scope grid barrier. Safe because grid == 256 blocks <= 256 CUs and
// per-CU resources (52KB LDS -> 3 blocks/CU, 4 waves) guarantee co-residency.
// Counters zeroed by hipMemsetAsync at the start of every kernel_launch.
__device__ __forceinline__ void grid_barrier(unsigned* bar, int idx) {
    __syncthreads();
    if (threadIdx.x == 0) {
        __threadfence();                       // release all prior stores
        atomicAdd(&bar[idx * 32], 1u);         // device-scope by default
        while (__hip_atomic_load(&bar[idx * 32], __ATOMIC_ACQUIRE,
                                 __HIP_MEMORY_SCOPE_AGENT) < (unsigned)NBLK) {
            __builtin_amdgcn_s_sleep(1);
        }
        __threadfence();
    }
    __syncthreads();
}

__global__ __launch_bounds__(NTHR) void mega_kernel(
    const float* __restrict__ TO,    // [B, L+1, HS]
    const float* __restrict__ Wd,    // [HS, HD]
    const float* __restrict__ bd,    // [HD]
    const float* __restrict__ Wc,    // [3*HD, C]
    const float* __restrict__ bc,    // [C]
    const int*   __restrict__ wm,    // [B, L]
    const int*   __restrict__ tokl,  // [B]
    const int*   __restrict__ len,   // [B]
    unsigned* bar,
    float* __restrict__ hs_s,        // [NROW, KP]
    float* __restrict__ WfT,         // [WJ, KP]  (transposed fused weights)
    float* __restrict__ part,        // [KS, NROW, WJ]
    float4* __restrict__ out)        // [B*N*N*C/4]
{
    const int blk = blockIdx.x;
    const int t   = threadIdx.x;

    __shared__ float sbuf[12288];    // 48 KB: Wc | wf-slice | finalize arrays
    __shared__ int   s_wm[B * L];
    __shared__ int   s_len[B], s_tok[B];
    __shared__ int   s_ss[3 * 2];    // start/stop per local pooling task
    __shared__ float s_ci[3];

    for (int e = t; e < B * L; e += NTHR) s_wm[e] = wm[e];
    if (t < B) { s_len[t] = len[t]; s_tok[t] = tokl[t]; }
    __syncthreads();

    // ======== phase 0: pooled row sums (tasks 0..639) + WfT (tasks 640..688)
    if (t < 3) {
        const int task = blk + NBLK * t;
        if (task < NROW) {
            const int b = task / N, n = task % N;
            const int ln = s_len[b];
            const int* map = s_wm + b * L;
            int lo = 0, hi = L;
            while (lo < hi) { int m = (lo + hi) >> 1; if (map[m] < n) lo = m + 1; else hi = m; }
            int lo2 = lo, hi2 = L;
            while (lo2 < hi2) { int m = (lo2 + hi2) >> 1; if (map[m] < n + 1) lo2 = m + 1; else hi2 = m; }
            const int start = lo < ln ? lo : ln;
            const int stop  = lo2 < ln ? lo2 : ln;
            s_ss[t * 2] = start; s_ss[t * 2 + 1] = stop;
            s_ci[t] = (stop > start) ? 1.0f / (float)(stop - start) : 0.0f;
        }
    }
    __syncthreads();

    for (int ti = 0; ti < 3; ++ti) {
        const int task = blk + NBLK * ti;
        if (task < NROW) {
            const int start = s_ss[ti * 2], stop = s_ss[ti * 2 + 1];
            const float ci = s_ci[ti];
            const int b = task / N;
            float a0 = 0.f, a1 = 0.f, a2 = 0.f;
            const float* base = TO + ((size_t)b * (L + 1) + 1) * HS;
            for (int l = start; l < stop; ++l) {
                const float* r = base + (size_t)l * HS;
                a0 += r[t]; a1 += r[t + 256]; a2 += r[t + 512];
            }
            float* hr = hs_s + (size_t)task * KP;
            hr[t] = a0 * ci; hr[t + 256] = a1 * ci; hr[t + 512] = a2 * ci;
            if (t < 16) hr[768 + t] = (t == 0 && ci > 0.f) ? 1.0f : 0.0f;
        } else if (task < NROW + 49) {
            const int wb = task - NROW;           // block-uniform branch
            __syncthreads();
            for (int e = t; e < 3 * HD * C; e += NTHR) sbuf[e] = Wc[e];
            __syncthreads();
            const int kl = t >> 4, c = t & 15;
            if (wb < 48) {
                const int k = wb * 16 + kl;
                const float4* wd4 = (const float4*)(Wd + (size_t)k * HD);
                float acc0 = 0.f, acc1 = 0.f, acc2 = 0.f;
                #pragma unroll 8
                for (int q = 0; q < HD / 4; ++q) {
                    const float4 w = wd4[q];
                    const int d = 4 * q;
                    acc0 += w.x * sbuf[d * C + c]              + w.y * sbuf[(d + 1) * C + c]
                          + w.z * sbuf[(d + 2) * C + c]        + w.w * sbuf[(d + 3) * C + c];
                    acc1 += w.x * sbuf[(HD + d) * C + c]       + w.y * sbuf[(HD + d + 1) * C + c]
                          + w.z * sbuf[(HD + d + 2) * C + c]   + w.w * sbuf[(HD + d + 3) * C + c];
                    acc2 += w.x * sbuf[(2*HD + d) * C + c]     + w.y * sbuf[(2*HD + d + 1) * C + c]
                          + w.z * sbuf[(2*HD + d + 2) * C + c] + w.w * sbuf[(2*HD + d + 3) * C + c];
                }
                WfT[(size_t)c * KP + k]        = acc0;
                WfT[(size_t)(16 + c) * KP + k] = acc1;
                WfT[(size_t)(32 + c) * KP + k] = acc2;
            } else {
                if (t < WJ) {                       // bias row k=768
                    const int m = t >> 4, cc = t & 15;
                    const float4* bd4 = (const float4*)bd;
                    float acc = 0.f;
                    #pragma unroll 8
                    for (int q = 0; q < HD / 4; ++q) {
                        const float4 w = bd4[q];
                        const int d = 4 * q;
                        acc += w.x * sbuf[(m * HD + d) * C + cc]     + w.y * sbuf[(m * HD + d + 1) * C + cc]
                             + w.z * sbuf[(m * HD + d + 2) * C + cc] + w.w * sbuf[(m * HD + d + 3) * C + cc];
                    }
                    WfT[(size_t)t * KP + 768] = acc;
                }
                for (int e = t; e < WJ * 15; e += NTHR) {   // zero rows 769..783
                    const int j = e / 15, k = 769 + e % 15;
                    WfT[(size_t)j * KP + k] = 0.f;
                }
            }
        }
    }

    grid_barrier(bar, 0);

    // ======== phase 1: split-k GEMM. Block's slice ks = blk&3 (both tasks share it).
    const int ks = blk & 3;
    const int k0 = ks * KSL;
    for (int e = t; e < WJ * KSL; e += NTHR) {       // stage wf-slice transposed [48][196]
        const int j = e / KSL, k = e % KSL;
        sbuf[j * KSL + k] = WfT[(size_t)j * KP + k0 + k];
    }
    __syncthreads();

    const int tj = t % WJ;
    const int tr = t / WJ;                           // 0..4 valid, 5 idle
    for (int ti = 0; ti < 2; ++ti) {
        const int task = blk + NBLK * ti;            // 0..511
        const int rg = task >> 2;                    // 0..127, 5 rows each
        if (tr < 5) {
            const int row = rg * 5 + tr;
            const float4* in = (const float4*)(hs_s + (size_t)row * KP + k0);
            const float4* wr = (const float4*)(sbuf + tj * KSL);
            float acc = 0.f;
            #pragma unroll 7
            for (int q = 0; q < KSL / 4; ++q) {
                const float4 v = in[q];
                const float4 w = wr[q];
                acc += v.x * w.x + v.y * w.y + v.z * w.z + v.w * w.w;
            }
            const int b = row / N, n = row % N;
            if (tj >= 32 && n >= s_tok[b]) acc = 0.f;
            part[((size_t)ks * NROW + row) * WJ + tj] = acc;
        }
    }

    grid_barrier(bar, 1);

    // ======== phase 2: reduce + scan + emit (blocks 0..79)
    if (blk < 80) {
        const int it = blk % 20;
        const int b  = blk / 20;
        const int tl = s_tok[b];
        float* sBT  = sbuf;              // [160*32]
        float* sA   = sbuf + 5120;       // [128]
        float* sS   = sbuf + 5248;       // [161*16]
        float* pref = sbuf + 7824;       // [256]

        for (int e = t; e < N * 32; e += NTHR) {
            const int n = e >> 5, j2 = e & 31;
            const size_t bse = ((size_t)b * N + n) * WJ + 16 + j2;
            sBT[e] = part[bse]
                   + part[(size_t)1 * NROW * WJ + bse]
                   + part[(size_t)2 * NROW * WJ + bse]
                   + part[(size_t)3 * NROW * WJ + bse];
        }
        if (t < 128) {
            const int il = t >> 4, c = t & 15;
            const size_t bse = ((size_t)b * N + it * 8 + il) * WJ + c;
            sA[t] = part[bse]
                  + part[(size_t)1 * NROW * WJ + bse]
                  + part[(size_t)2 * NROW * WJ + bse]
                  + part[(size_t)3 * NROW * WJ + bse];
        }
        if (t < 16) sS[t] = 0.f;
        __syncthreads();

        const int c = t & 15, g = t >> 4;            // 16 chunks of 10
        const int nb = g * 10;
        {
            float run = 0.f;
            for (int u = 0; u < 10; ++u) {
                run += sBT[(nb + u) * 32 + 16 + c];
                sS[(nb + u + 1) * 16 + c] = run;
            }
            pref[g * 16 + c] = run;
        }
        __syncthreads();
        if (t < 16) {
            float off = 0.f;
            for (int g2 = 0; g2 < 16; ++g2) {
                const float tmp = pref[g2 * 16 + t];
                pref[g2 * 16 + t] = off;
                off += tmp;
            }
        }
        __syncthreads();
        {
            const float off = pref[g * 16 + c];
            for (int u = 0; u < 10; ++u) sS[(nb + u + 1) * 16 + c] += off;
        }
        __syncthreads();

        for (int q = 0; q < 20; ++q) {
            const int qid = t + q * NTHR;
            const int cq  = qid & 3;
            const int k   = (qid >> 2) % N;
            const int il  = (qid >> 2) / N;
            const int i   = it * 8 + il;

            float4 v = {0.f, 0.f, 0.f, 0.f};
            if ((i <= k) & (i < tl) & (k < tl)) {
                const float4 a   = *(const float4*)&sA[il * 16 + cq * 4];
                const float4 bb  = *(const float4*)&sBT[k * 32 + cq * 4];
                const float4 sk  = *(const float4*)&sS[(k + 1) * 16 + cq * 4];
                const float4 si  = *(const float4*)&sS[i * 16 + cq * 4];
                const float4 bcq = *(const float4*)&bc[cq * 4];
                const float inv = 1.0f / (float)(k - i + 1);
                v.x = a.x + bb.x + (sk.x - si.x) * inv + bcq.x;
                v.y = a.y + bb.y + (sk.y - si.y) * inv + bcq.y;
                v.z = a.z + bb.z + (sk.z - si.z) * inv + bcq.z;
                v.w = a.w + bb.w + (sk.w - si.w) * inv + bcq.w;
            }
            out[((size_t)(b * N + i) * N + k) * 4 + cq] = v;
        }
    }
}

extern "C" void kernel_launch(void* const* d_in, const int* in_sizes, int n_in,
                              void* d_out, int out_size, void* d_ws, size_t ws_size,
                              hipStream_t stream) {
    const float* TO   = (const float*)d_in[0];
    const float* Wd   = (const float*)d_in[1];
    const float* bd   = (const float*)d_in[2];
    const float* Wc   = (const float*)d_in[3];
    const float* bc   = (const float*)d_in[4];
    const int*   wm   = (const int*)d_in[5];
    const int*   tokl = (const int*)d_in[6];
    const int*   lenp = (const int*)d_in[7];

    unsigned* bar = (unsigned*)d_ws;                 // 256 B barrier area
    float* base   = (float*)d_ws + 64;
    float* hs_s   = base;                            // 640*784
    float* WfT    = hs_s + (size_t)NROW * KP;        // 48*784
    float* part   = WfT + (size_t)WJ * KP;           // 4*640*48
    // ~2.65 MB of ws; every element written before read on every call.

    hipMemsetAsync(bar, 0, 256, stream);             // reset barrier counters
    mega_kernel<<<NBLK, NTHR, 0, stream>>>(TO, Wd, bd, Wc, bc, wm, tokl, lenp,
                                           bar, hs_s, WfT, part, (float4*)d_out);
}

// Round 6
// 30.852 us; speedup vs baseline: 3.2590x; 3.2590x over previous
//
#include <hip/hip_runtime.h>

#define B 4
#define L 200
#define N 160
#define HS 768
#define HD 256
#define C 16

#define KP 784             // padded K: 768 data + 1 gate(bias) + 15 zero
#define WJ 48              // fused cols: A(16) | B(16) | T(16)
#define KS 4               // split-k slices
#define KSL (KP / KS)      // 196
#define NROW (B * N)       // 640
#define WCT_STRIDE 260     // 65 float4s: odd quad-stride -> conflict-free b128

// ---------------------------------------------------------------------------
// K1  blocks 0..639        : pooling -> hs_s row (768 data + gate + zeros)
//     blocks 640..786 (147): WfT[(m*16+c)][k-stripe] = Wd[k,:] . Wc_m[:,c]
//                            (one 16-k-stripe x one m-block per block;
//                             Wc_m transposed in LDS, float4 dots both sides)
//     block  787           : bias row k=768 (bd . Wc_m[:,c]) + zero rows 769..783
// ---------------------------------------------------------------------------
__global__ __launch_bounds__(256) void prep_kernel(
    const float* __restrict__ TO,      // [B, L+1, HS]
    const float* __restrict__ Wd,      // [HS, HD]
    const float* __restrict__ bd,      // [HD]
    const float* __restrict__ Wc,      // [3*HD, C]
    const int*   __restrict__ wm,      // [B, L]
    const int*   __restrict__ lengths, // [B]
    float* __restrict__ hs_s,          // [NROW, KP]
    float* __restrict__ WfT)           // [WJ, KP]  (j-major, transposed)
{
    const int blk = blockIdx.x;
    const int t = threadIdx.x;

    if (blk < NROW) {
        const int row = blk;
        const int b = row / N, n = row % N;
        const int len = lengths[b];

        __shared__ int smap[L];
        for (int e = t; e < L; e += 256) smap[e] = wm[b * L + e];
        __syncthreads();

        int lo = 0, hi = L;
        while (lo < hi) { int m = (lo + hi) >> 1; if (smap[m] < n) lo = m + 1; else hi = m; }
        int lo2 = lo, hi2 = L;
        while (lo2 < hi2) { int m = (lo2 + hi2) >> 1; if (smap[m] < n + 1) lo2 = m + 1; else hi2 = m; }
        const int start = lo < len ? lo : len;
        const int stop  = lo2 < len ? lo2 : len;
        const int cnt   = stop - start;
        const float ci  = (cnt > 0) ? 1.0f / (float)cnt : 0.0f;

        float a0 = 0.f, a1 = 0.f, a2 = 0.f;
        const float* base = TO + ((size_t)b * (L + 1) + 1) * HS;
        for (int l = start; l < stop; ++l) {
            const float* r = base + (size_t)l * HS;
            a0 += r[t]; a1 += r[t + 256]; a2 += r[t + 512];
        }
        float* hr = hs_s + (size_t)row * KP;
        hr[t] = a0 * ci; hr[t + 256] = a1 * ci; hr[t + 512] = a2 * ci;
        if (t < 16) hr[768 + t] = (t == 0 && cnt > 0) ? 1.0f : 0.0f;
    } else if (blk < NROW + 147) {
        const int wb = blk - NROW;          // 0..146
        const int kb = wb / 3;              // k-stripe 0..48
        const int m  = wb % 3;              // Wc block

        __shared__ float wcT[16 * WCT_STRIDE];   // Wc_m transposed [c][d]
        for (int e = t; e < HD * C; e += 256) {
            const int d = e >> 4, c = e & 15;    // Wc read coalesced (c fast)
            wcT[c * WCT_STRIDE + d] = Wc[(size_t)(m * HD + d) * C + c];
        }
        __syncthreads();

        const int kl = t >> 4, c = t & 15;
        const int k = kb * 16 + kl;
        const float4* wd4 = (const float4*)(Wd + (size_t)k * HD);   // L1-bcast x16 c
        const float4* wc4 = (const float4*)(wcT + c * WCT_STRIDE);  // conflict-free
        float acc = 0.f;
        #pragma unroll 8
        for (int q = 0; q < HD / 4; ++q) {
            const float4 a = wd4[q];
            const float4 w = wc4[q];
            acc += a.x * w.x + a.y * w.y + a.z * w.z + a.w * w.w;
        }
        WfT[(size_t)(m * 16 + c) * KP + k] = acc;
    } else {
        // bias row (k=768) and zero rows 769..783
        if (t < WJ) {
            const int m = t >> 4, c = t & 15;
            const float4* bd4 = (const float4*)bd;
            float acc = 0.f;
            #pragma unroll 8
            for (int q = 0; q < HD / 4; ++q) {
                const float4 w = bd4[q];
                const int d = 4 * q;
                acc += w.x * Wc[(size_t)(m * HD + d) * C + c]
                     + w.y * Wc[(size_t)(m * HD + d + 1) * C + c]
                     + w.z * Wc[(size_t)(m * HD + d + 2) * C + c]
                     + w.w * Wc[(size_t)(m * HD + d + 3) * C + c];
            }
            WfT[(size_t)t * KP + 768] = acc;
        }
        for (int e = t; e < WJ * 15; e += 256) {
            const int j = e / 15, k = 769 + e % 15;
            WfT[(size_t)j * KP + k] = 0.f;
        }
    }
}

// ---------------------------------------------------------------------------
// K2: split-k GEMM  part[s,row,j] = sum_{k in slice s} hs_s[row,k] * WfT[j,k]
//     j-slice of WfT staged in LDS [48][196] (coalesced load, ~conflict-free).
//     T cols (j>=32) gated by token mask. 192 thr = 48 j x 4 rows.
// ---------------------------------------------------------------------------
__global__ __launch_bounds__(192) void gemm_kernel(
    const float* __restrict__ hs_s,    // [NROW, KP]
    const float* __restrict__ WfT,     // [WJ, KP]
    const int*   __restrict__ token_length,
    float* __restrict__ part)          // [KS, NROW, WJ]
{
    const int t  = threadIdx.x;
    const int tj = t % WJ;
    const int tr = t / WJ;                       // 0..3
    const int row = blockIdx.y * 4 + tr;
    const int k0  = blockIdx.x * KSL;

    __shared__ float sbuf[WJ * KSL];             // 36.75 KB
    for (int e = t; e < WJ * KSL; e += 192) {    // k fast -> global coalesced,
        const int j = e / KSL, k = e % KSL;      // LDS write 2-way max
        sbuf[j * KSL + k] = WfT[(size_t)j * KP + k0 + k];
    }
    __syncthreads();

    const float4* in = (const float4*)(hs_s + (size_t)row * KP + k0);
    const float4* wr = (const float4*)(sbuf + tj * KSL);   // 49-quad stride: coprime w/ 8
    float acc = 0.f;
    #pragma unroll 7
    for (int q = 0; q < KSL / 4; ++q) {
        const float4 v = in[q];
        const float4 w = wr[q];
        acc += v.x * w.x + v.y * w.y + v.z * w.z + v.w * w.w;
    }
    const int b = row / N, n = row % N;
    if (tj >= 32 && n >= token_length[b]) acc = 0.f;
    part[((size_t)blockIdx.x * NROW + row) * WJ + tj] = acc;
}

// ---------------------------------------------------------------------------
// K3: per (b, i-tile of 8): reduce split-k partials into LDS, blocked scan of
//     T -> S, emit logits tile with coalesced float4 stores.
// ---------------------------------------------------------------------------
__global__ __launch_bounds__(256) void finalize_kernel(
    const float* __restrict__ part,    // [KS, NROW, WJ]
    const float* __restrict__ bc,      // [C]
    const int*   __restrict__ token_length,
    float4* __restrict__ out)          // [B*N*N*C/4]
{
    const int it = blockIdx.x;         // 0..19
    const int b  = blockIdx.y;         // 0..3
    const int t  = threadIdx.x;
    const int tl = token_length[b];

    __shared__ float sBT[N * 32];      // [n][j2]: j2 0..15 = B, 16..31 = T
    __shared__ float sA[8 * 16];
    __shared__ float sS[(N + 1) * 16]; // inclusive cumsum, sS[0..15] = 0
    __shared__ float pref[16 * 16];

    for (int e = t; e < N * 32; e += 256) {
        const int n = e >> 5, j2 = e & 31;
        const size_t bse = ((size_t)b * N + n) * WJ + 16 + j2;
        sBT[e] = part[bse]
               + part[(size_t)1 * NROW * WJ + bse]
               + part[(size_t)2 * NROW * WJ + bse]
               + part[(size_t)3 * NROW * WJ + bse];
    }
    if (t < 128) {
        const int il = t >> 4, c = t & 15;
        const size_t bse = ((size_t)b * N + it * 8 + il) * WJ + c;
        sA[t] = part[bse]
              + part[(size_t)1 * NROW * WJ + bse]
              + part[(size_t)2 * NROW * WJ + bse]
              + part[(size_t)3 * NROW * WJ + bse];
    }
    if (t < 16) sS[t] = 0.f;
    __syncthreads();

    const int c = t & 15, g = t >> 4;            // 16 chunks of 10
    const int nb = g * 10;
    {
        float run = 0.f;
        for (int u = 0; u < 10; ++u) {
            run += sBT[(nb + u) * 32 + 16 + c];
            sS[(nb + u + 1) * 16 + c] = run;
        }
        pref[g * 16 + c] = run;
    }
    __syncthreads();
    if (t < 16) {
        float off = 0.f;
        for (int g2 = 0; g2 < 16; ++g2) {
            const float tmp = pref[g2 * 16 + t];
            pref[g2 * 16 + t] = off;
            off += tmp;
        }
    }
    __syncthreads();
    {
        const float off = pref[g * 16 + c];
        for (int u = 0; u < 10; ++u) sS[(nb + u + 1) * 16 + c] += off;
    }
    __syncthreads();

    for (int q = 0; q < 20; ++q) {
        const int qid = t + q * 256;
        const int cq  = qid & 3;
        const int k   = (qid >> 2) % N;
        const int il  = (qid >> 2) / N;
        const int i   = it * 8 + il;

        float4 v = {0.f, 0.f, 0.f, 0.f};
        if ((i <= k) & (i < tl) & (k < tl)) {
            const float4 a   = *(const float4*)&sA[il * 16 + cq * 4];
            const float4 bb  = *(const float4*)&sBT[k * 32 + cq * 4];
            const float4 sk  = *(const float4*)&sS[(k + 1) * 16 + cq * 4];
            const float4 si  = *(const float4*)&sS[i * 16 + cq * 4];
            const float4 bcq = *(const float4*)&bc[cq * 4];
            const float inv = 1.0f / (float)(k - i + 1);
            v.x = a.x + bb.x + (sk.x - si.x) * inv + bcq.x;
            v.y = a.y + bb.y + (sk.y - si.y) * inv + bcq.y;
            v.z = a.z + bb.z + (sk.z - si.z) * inv + bcq.z;
            v.w = a.w + bb.w + (sk.w - si.w) * inv + bcq.w;
        }
        out[((size_t)(b * N + i) * N + k) * 4 + cq] = v;
    }
}

extern "C" void kernel_launch(void* const* d_in, const int* in_sizes, int n_in,
                              void* d_out, int out_size, void* d_ws, size_t ws_size,
                              hipStream_t stream) {
    const float* TO   = (const float*)d_in[0];
    const float* Wd   = (const float*)d_in[1];
    const float* bd   = (const float*)d_in[2];
    const float* Wc   = (const float*)d_in[3];
    const float* bc   = (const float*)d_in[4];
    const int*   wm   = (const int*)d_in[5];
    const int*   tokl = (const int*)d_in[6];
    const int*   lenp = (const int*)d_in[7];

    float* ws   = (float*)d_ws;
    float* hs_s = ws;                                // 640*784
    float* WfT  = hs_s + (size_t)NROW * KP;          // 48*784
    float* part = WfT + (size_t)WJ * KP;             // 4*640*48
    // ~2.65 MB of ws; every element written before read on every call.

    prep_kernel<<<NROW + 147 + 1, 256, 0, stream>>>(TO, Wd, bd, Wc, wm, lenp, hs_s, WfT);
    gemm_kernel<<<dim3(KS, NROW / 4), 192, 0, stream>>>(hs_s, WfT, tokl, part);
    finalize_kernel<<<dim3(20, B), 256, 0, stream>>>(part, bc, tokl, (float4*)d_out);
}